// Round 6
// baseline (96.925 us; speedup 1.0000x reference)
//
#include <hip/hip_runtime.h>
#include <hip/hip_bf16.h>

// Glow coupling layer, fused. rows N = 262144, C = 64.
// r2 = MLP_s2(x2); y1 = e(s2)*x1 + t2; r1 = MLP_s1(y1); y2 = e(s1)*x2 + t1.
//
// Round 6: wave-independent. Each wave owns 16 rows end-to-end; per-wave
// h1/h2 (4KB each, XOR-swizzled [16][256B]) -> ZERO __syncthreads (in-order
// per-wave DS pipe). L1 input frags built in registers from global (no LDS).
// s/t pairs land in the same lane/reg (acc tiles 0,1 vs 2,3) -> in-lane
// epilogue: 8 e_fun/lane, no shuffles, all lanes useful. Weights JIT per
// f-tile. LB(256,4): VGPR cap 128, no spill, 4 blocks/CU.
//
// MFMA v_mfma_f32_16x16x32_bf16, W = A-operand, activations = B-operand:
//   A frag: lane l holds A[row=l&15][k=(l>>4)*8+j]
//   B frag: lane l holds B[k=(l>>4)*8+j][col=l&15]
//   D     : lane l reg i -> (feat = 4*(l>>4)+i, col-row = l&15)  [m89/m91]

using bf16x8 = __attribute__((ext_vector_type(8))) short;
using f32x4  = __attribute__((ext_vector_type(4))) float;
using u32x2  = __attribute__((ext_vector_type(2))) unsigned int;

__device__ __forceinline__ unsigned short f2bf(float f) {
    unsigned int u = __float_as_uint(f);
    u += 0x7FFFu + ((u >> 16) & 1u);
    return (unsigned short)(u >> 16);
}
__device__ __forceinline__ unsigned int pk2bf(float a, float b) {
    union { __hip_bfloat162 h; unsigned int u; } cv;
    cv.h = __float22bfloat162_rn(float2{a, b});
    return cv.u;   // low16 = bf16(a), high16 = bf16(b)
}
__device__ __forceinline__ float lo16f(unsigned int u) { return __uint_as_float(u << 16); }
__device__ __forceinline__ float hi16f(unsigned int u) { return __uint_as_float(u & 0xFFFF0000u); }

__device__ __forceinline__ f32x4 mfma16(bf16x8 a, bf16x8 b, f32x4 c) {
    return __builtin_amdgcn_mfma_f32_16x16x32_bf16(a, b, c, 0, 0, 0);
}

// e(s) = exp(3.18*atan(s/5)) = exp2(4.5877702*atan(0.2 s)); deg-11 minimax.
__device__ __forceinline__ float e_fun(float s) {
    float z = 0.2f * s;
    float a = fabsf(z);
    float t = fminf(a, __builtin_amdgcn_rcpf(a));   // a<=1 ? a : 1/a
    float u = t * t;
    float p = -0.0537741f;
    p = fmaf(p, u,  0.2415614f);
    p = fmaf(p, u, -0.5341673f);
    p = fmaf(p, u,  0.8879339f);
    p = fmaf(p, u, -1.5260000f);
    p = fmaf(p, u,  4.5876659f);
    p = p * t;
    float r = (a > 1.0f) ? (7.2064613f - p) : p;    // K*pi/2 - p
    r = copysignf(r, s);
    return __builtin_amdgcn_exp2f(r);
}

// per-wave LDS: h1 4096 @0, h2 4096 @4096. scratch (hi 1280 + lo 1280) aliases h1.
#define WAVE_LDS 8192
#define LDS_BYTES 32768

#define BIAS_OFF 114688           // 112 tiles * 1024B
#define WS_NEED  (114688 + 2560)

struct WPtrs { const float *w1, *b1, *w2, *b2, *w3, *b3; };

__device__ __forceinline__ bf16x8 load_wfrag(const float* __restrict__ W, int K, int frow, int k0) {
    const float4* p = reinterpret_cast<const float4*>(W + (size_t)frow * K + k0);
    float4 a = p[0], b = p[1];
    bf16x8 r;
    r[0] = (short)f2bf(a.x); r[1] = (short)f2bf(a.y);
    r[2] = (short)f2bf(a.z); r[3] = (short)f2bf(a.w);
    r[4] = (short)f2bf(b.x); r[5] = (short)f2bf(b.y);
    r[6] = (short)f2bf(b.z); r[7] = (short)f2bf(b.w);
    return r;
}

template<int MODE>
__device__ __forceinline__ bf16x8 get_frag(const char* wsb, const WPtrs& P, int mlp,
                                           int tile, int which, int row, int k0, int lane) {
    if constexpr (MODE != 0) {
        union { uint4 q; bf16x8 v; } u;
        u.q = reinterpret_cast<const uint4*>(wsb)[(mlp * 56 + tile) * 64 + lane];
        return u.v;
    } else {
        const float* W = (which == 0) ? P.w1 : (which == 1) ? P.w2 : P.w3;
        return load_wfrag(W, (which == 0) ? 32 : 128, row, k0);
    }
}

// ---- full 3-layer MLP for this wave's 16 rows; barrier-free ----
// bhi/blo: input B-frags (lane: in[k=8lg+j][row=lr]).
// acc3[t]: L3 out, feats 16t+4lg+i, row lr. Tiles 0,1 = s; 2,3 = t-vals.
template<int MODE>
__device__ __forceinline__ void run_mlp(const char* __restrict__ wsb, const WPtrs& P, int mlp,
    bf16x8 bhi, bf16x8 blo, char* __restrict__ h1, char* __restrict__ h2,
    int lg, int lr, int lane, f32x4 (&acc3)[4])
{
    const int sw = (lr & 7) << 4;
    const float* bias = reinterpret_cast<const float*>(wsb + BIAS_OFF) + mlp * 320;

    // -------- layer 1: K=32 (hi+lo), out feats 0..127 -> h1 --------
    #pragma unroll
    for (int t = 0; t < 8; ++t) {
        bf16x8 w = get_frag<MODE>(wsb, P, mlp, t, 0, 16 * t + lr, 8 * lg, lane);
        f32x4 acc = MODE ? *reinterpret_cast<const f32x4*>(bias + 16 * t + 4 * lg)
                         : *reinterpret_cast<const f32x4*>(P.b1 + 16 * t + 4 * lg);
        acc = mfma16(w, bhi, acc);
        acc = mfma16(w, blo, acc);
        u32x2 pp = { pk2bf(fmaxf(acc[0], 0.f), fmaxf(acc[1], 0.f)),
                     pk2bf(fmaxf(acc[2], 0.f), fmaxf(acc[3], 0.f)) };
        *reinterpret_cast<u32x2*>(h1 + lr * 256 + ((32 * t + 8 * lg) ^ sw)) = pp;
    }

    // -------- layer 2: K=128, h1 -> h2 --------
    bf16x8 hf[4];
    #pragma unroll
    for (int ks = 0; ks < 4; ++ks)
        hf[ks] = *reinterpret_cast<const bf16x8*>(h1 + lr * 256 + ((64 * ks + 16 * lg) ^ sw));
    #pragma unroll
    for (int t = 0; t < 8; ++t) {
        f32x4 acc = MODE ? *reinterpret_cast<const f32x4*>(bias + 128 + 16 * t + 4 * lg)
                         : *reinterpret_cast<const f32x4*>(P.b2 + 16 * t + 4 * lg);
        #pragma unroll
        for (int ks = 0; ks < 4; ++ks) {
            bf16x8 w = get_frag<MODE>(wsb, P, mlp, 8 + 4 * t + ks, 1,
                                      16 * t + lr, 32 * ks + 8 * lg, lane);
            acc = mfma16(w, hf[ks], acc);
        }
        u32x2 pp = { pk2bf(fmaxf(acc[0], 0.f), fmaxf(acc[1], 0.f)),
                     pk2bf(fmaxf(acc[2], 0.f), fmaxf(acc[3], 0.f)) };
        *reinterpret_cast<u32x2*>(h2 + lr * 256 + ((32 * t + 8 * lg) ^ sw)) = pp;
    }

    // -------- layer 3: K=128, h2 -> acc3 (kept in regs) --------
    bf16x8 hg[4];
    #pragma unroll
    for (int ks = 0; ks < 4; ++ks)
        hg[ks] = *reinterpret_cast<const bf16x8*>(h2 + lr * 256 + ((64 * ks + 16 * lg) ^ sw));
    #pragma unroll
    for (int t = 0; t < 4; ++t) {
        f32x4 acc = MODE ? *reinterpret_cast<const f32x4*>(bias + 256 + 16 * t + 4 * lg)
                         : *reinterpret_cast<const f32x4*>(P.b3 + 16 * t + 4 * lg);
        #pragma unroll
        for (int ks = 0; ks < 4; ++ks) {
            bf16x8 w = get_frag<MODE>(wsb, P, mlp, 40 + 4 * t + ks, 2,
                                      16 * t + lr, 32 * ks + 8 * lg, lane);
            acc = mfma16(w, hg[ks], acc);
        }
        acc3[t] = acc;
    }
}

// ---- weight prep: fragment tiles (1KB each) + plain biases into d_ws ----
extern "C" __global__ void __launch_bounds__(256)
glow_prep(const float* __restrict__ s2w1, const float* __restrict__ s2w2,
          const float* __restrict__ s2w3, const float* __restrict__ s1w1,
          const float* __restrict__ s1w2, const float* __restrict__ s1w3,
          const float* __restrict__ s2b1, const float* __restrict__ s2b2,
          const float* __restrict__ s2b3, const float* __restrict__ s1b1,
          const float* __restrict__ s1b2, const float* __restrict__ s1b3,
          char* __restrict__ wsb)
{
    const int wave = threadIdx.x >> 6, lane = threadIdx.x & 63;
    const int lr = lane & 15, lg = lane >> 4;
    const int gw = blockIdx.x * 4 + wave;

    if (gw < 112) {
        int mlp = gw / 56, t = gw % 56;
        const float* Ws[2][3] = {{s2w1, s2w2, s2w3}, {s1w1, s1w2, s1w3}};
        const float* W; int K, row, k0;
        if (t < 8)       { W = Ws[mlp][0]; K = 32;  row = 16 * t + lr;          k0 = lg * 8; }
        else if (t < 40) { int u = t - 8;  W = Ws[mlp][1]; K = 128; row = 16 * (u >> 2) + lr; k0 = 32 * (u & 3) + lg * 8; }
        else             { int u = t - 40; W = Ws[mlp][2]; K = 128; row = 16 * (u >> 2) + lr; k0 = 32 * (u & 3) + lg * 8; }
        const float* p = W + (size_t)row * K + k0;
        union U { uint4 q; bf16x8 v; } u;
        #pragma unroll
        for (int j = 0; j < 8; ++j) u.v[j] = (short)f2bf(p[j]);
        reinterpret_cast<uint4*>(wsb)[gw * 64 + lane] = u.q;
    } else if (blockIdx.x == 28) {
        const float* Bs[2][3] = {{s2b1, s2b2, s2b3}, {s1b1, s1b2, s1b3}};
        float* dst = reinterpret_cast<float*>(wsb + BIAS_OFF);
        for (int i = threadIdx.x; i < 640; i += 256) {
            int mlp = i / 320, j = i % 320;
            float v;
            if (j < 128)      v = Bs[mlp][0][j];
            else if (j < 256) v = Bs[mlp][1][j - 128];
            else              v = Bs[mlp][2][j - 256];
            dst[i] = v;
        }
    }
}

template<int MODE>
__global__ void __launch_bounds__(256, 4)
glow_main(const float* __restrict__ x,
          const float* __restrict__ s1w1, const float* __restrict__ s1b1,
          const float* __restrict__ s1w2, const float* __restrict__ s1b2,
          const float* __restrict__ s1w3, const float* __restrict__ s1b3,
          const float* __restrict__ s2w1, const float* __restrict__ s2b1,
          const float* __restrict__ s2w2, const float* __restrict__ s2b2,
          const float* __restrict__ s2w3, const float* __restrict__ s2b3,
          const char* __restrict__ wsb, float* __restrict__ out)
{
    __shared__ __align__(16) char lds[LDS_BYTES];

    const int tid  = threadIdx.x;
    const int wave = tid >> 6, lane = tid & 63;
    const int lr = lane & 15, lg = lane >> 4;

    char* wlds = lds + wave * WAVE_LDS;
    char* h1 = wlds;                 // 4096
    char* h2 = wlds + 4096;          // 4096
    char* shi = wlds;                // scratch hi, aliases h1 (dead between MLPs)
    char* slo = wlds + 1280;         // scratch lo

    const size_t row = (size_t)blockIdx.x * 64 + 16 * wave + lr;
    const float* gx  = x   + row * 64;
    float*       go  = out + row * 64;

    const WPtrs P[2] = {{s2w1, s2b1, s2w2, s2b2, s2w3, s2b3},
                        {s1w1, s1b1, s1w2, s1b2, s1w3, s1b3}};

    // ---- x2 B-frags straight from global: lane needs x2[lr][8lg..8lg+7] ----
    f32x4 xa = *reinterpret_cast<const f32x4*>(gx + 32 + 8 * lg);
    f32x4 xb = *reinterpret_cast<const f32x4*>(gx + 36 + 8 * lg);
    union FB { bf16x8 v; unsigned int u[4]; };
    FB Hf, Lf;
    Hf.u[0] = pk2bf(xa[0], xa[1]);  Hf.u[1] = pk2bf(xa[2], xa[3]);
    Hf.u[2] = pk2bf(xb[0], xb[1]);  Hf.u[3] = pk2bf(xb[2], xb[3]);
    Lf.u[0] = pk2bf(xa[0] - lo16f(Hf.u[0]), xa[1] - hi16f(Hf.u[0]));
    Lf.u[1] = pk2bf(xa[2] - lo16f(Hf.u[1]), xa[3] - hi16f(Hf.u[1]));
    Lf.u[2] = pk2bf(xb[0] - lo16f(Hf.u[2]), xb[1] - hi16f(Hf.u[2]));
    Lf.u[3] = pk2bf(xb[2] - lo16f(Hf.u[3]), xb[3] - hi16f(Hf.u[3]));

    f32x4 a3[4];

    // ---- MLP s2 on x2 ----
    run_mlp<MODE>(wsb, P[0], 0, Hf.v, Lf.v, h1, h2, lg, lr, lane, a3);

    // ---- epilogue 1: y1 = e(s2)*x1 + t2 -> out cols 0..31 + scratch planes ----
    {
        f32x4 xv0 = *reinterpret_cast<const f32x4*>(gx + 4 * lg);
        f32x4 xv1 = *reinterpret_cast<const f32x4*>(gx + 16 + 4 * lg);
        #pragma unroll
        for (int t = 0; t < 2; ++t) {
            const f32x4 xv = t ? xv1 : xv0;
            f32x4 y;
            #pragma unroll
            for (int i = 0; i < 4; ++i)
                y[i] = fmaf(e_fun(a3[t][i]), xv[i], a3[t + 2][i]);
            *reinterpret_cast<f32x4*>(go + 16 * t + 4 * lg) = y;
            unsigned int h0 = pk2bf(y[0], y[1]), h1p = pk2bf(y[2], y[3]);
            unsigned int l0 = pk2bf(y[0] - lo16f(h0),  y[1] - hi16f(h0));
            unsigned int l1 = pk2bf(y[2] - lo16f(h1p), y[3] - hi16f(h1p));
            *reinterpret_cast<u32x2*>(shi + lr * 80 + 32 * t + 8 * lg) = u32x2{h0, h1p};
            *reinterpret_cast<u32x2*>(slo + lr * 80 + 32 * t + 8 * lg) = u32x2{l0, l1};
        }
    }
    // read back y1 as B-frags (wave-local, in-order DS pipe; no barrier)
    bf16x8 yhi = *reinterpret_cast<const bf16x8*>(shi + lr * 80 + 16 * lg);
    bf16x8 ylo = *reinterpret_cast<const bf16x8*>(slo + lr * 80 + 16 * lg);

    // ---- MLP s1 on y1 ----
    run_mlp<MODE>(wsb, P[1], 1, yhi, ylo, h1, h2, lg, lr, lane, a3);

    // ---- epilogue 2: y2 = e(s1)*x2 + t1 -> out cols 32..63 ----
    {
        f32x4 xv0 = *reinterpret_cast<const f32x4*>(gx + 32 + 4 * lg);
        f32x4 xv1 = *reinterpret_cast<const f32x4*>(gx + 48 + 4 * lg);
        #pragma unroll
        for (int t = 0; t < 2; ++t) {
            const f32x4 xv = t ? xv1 : xv0;
            f32x4 y;
            #pragma unroll
            for (int i = 0; i < 4; ++i)
                y[i] = fmaf(e_fun(a3[t][i]), xv[i], a3[t + 2][i]);
            *reinterpret_cast<f32x4*>(go + 32 + 16 * t + 4 * lg) = y;
        }
    }
}

extern "C" void kernel_launch(void* const* d_in, const int* in_sizes, int n_in,
                              void* d_out, int out_size, void* d_ws, size_t ws_size,
                              hipStream_t stream) {
    const float* x    = (const float*)d_in[0];
    const float* s1w1 = (const float*)d_in[1];
    const float* s1b1 = (const float*)d_in[2];
    const float* s1w2 = (const float*)d_in[3];
    const float* s1b2 = (const float*)d_in[4];
    const float* s1w3 = (const float*)d_in[5];
    const float* s1b3 = (const float*)d_in[6];
    const float* s2w1 = (const float*)d_in[7];
    const float* s2b1 = (const float*)d_in[8];
    const float* s2w2 = (const float*)d_in[9];
    const float* s2b2 = (const float*)d_in[10];
    const float* s2w3 = (const float*)d_in[11];
    const float* s2b3 = (const float*)d_in[12];
    float* out = (float*)d_out;
    char* wsb  = (char*)d_ws;

    int nrows   = in_sizes[0] / 64;   // 262144
    int nblocks = nrows / 64;         // 4096

    if (ws_size >= (size_t)WS_NEED) {
        hipLaunchKernelGGL(glow_prep, dim3(29), dim3(256), 0, stream,
                           s2w1, s2w2, s2w3, s1w1, s1w2, s1w3,
                           s2b1, s2b2, s2b3, s1b1, s1b2, s1b3, wsb);
        hipLaunchKernelGGL((glow_main<1>), dim3(nblocks), dim3(256), 0, stream,
                           x, s1w1, s1b1, s1w2, s1b2, s1w3, s1b3,
                           s2w1, s2b1, s2w2, s2b2, s2w3, s2b3, wsb, out);
    } else {
        hipLaunchKernelGGL((glow_main<0>), dim3(nblocks), dim3(256), 0, stream,
                           x, s1w1, s1b1, s1w2, s1b2, s1w3, s1b3,
                           s2w1, s2b1, s2w2, s2b2, s2w3, s2b3, wsb, out);
    }
}